// Round 3
// baseline (1303.356 us; speedup 1.0000x reference)
//
#include <hip/hip_runtime.h>
#include <math.h>

#define NN 100000
#define NE 1600000
#define EPSBN 1e-5f
#define NB_SCAN 391   // ceil(NN/256)

// ---------------- bf16 helpers (manual, no header-API dependence) ----------------
static __device__ __forceinline__ unsigned short f2bf(float f) {
    unsigned int u = __float_as_uint(f);
    u += 0x7fffu + ((u >> 16) & 1u);   // round-to-nearest-even
    return (unsigned short)(u >> 16);
}
static __device__ __forceinline__ float bf2f(unsigned short s) {
    return __uint_as_float(((unsigned int)s) << 16);
}
static __device__ __forceinline__ void fma4(float4& a, float s, const float4& w) {
    a.x = fmaf(s, w.x, a.x); a.y = fmaf(s, w.y, a.y);
    a.z = fmaf(s, w.z, a.z); a.w = fmaf(s, w.w, a.w);
}
static __device__ __forceinline__ void fma2(float2& a, float s, const float2& w) {
    a.x = fmaf(s, w.x, a.x); a.y = fmaf(s, w.y, a.y);
}

// ---------------- CSR build ----------------
__global__ __launch_bounds__(256) void zero_cnt(int* __restrict__ cnt) {
    int i = blockIdx.x * 256 + threadIdx.x;
    if (i < NN) cnt[i] = 0;
}

__global__ __launch_bounds__(256) void hist_kernel(const int* __restrict__ dst,
                                                   int* __restrict__ cnt) {
    int e = blockIdx.x * 256 + threadIdx.x;
    if (e < NE) atomicAdd(&cnt[dst[e]], 1);
}

__global__ __launch_bounds__(256) void scan1(const int* __restrict__ cnt,
                                             int* __restrict__ rex,
                                             int* __restrict__ part) {
    __shared__ int sh[256];
    int t = threadIdx.x;
    int i = blockIdx.x * 256 + t;
    int val = (i < NN) ? cnt[i] : 0;
    sh[t] = val;
    __syncthreads();
    for (int off = 1; off < 256; off <<= 1) {
        int x = (t >= off) ? sh[t - off] : 0;
        __syncthreads();
        sh[t] += x;
        __syncthreads();
    }
    if (i < NN) rex[i] = sh[t] - val;
    if (t == 255) part[blockIdx.x] = sh[255];
}

__global__ __launch_bounds__(512) void scan2(const int* __restrict__ part,
                                             int* __restrict__ partoff) {
    __shared__ int sh[512];
    int t = threadIdx.x;
    int val = (t < NB_SCAN) ? part[t] : 0;
    sh[t] = val;
    __syncthreads();
    for (int off = 1; off < 512; off <<= 1) {
        int x = (t >= off) ? sh[t - off] : 0;
        __syncthreads();
        sh[t] += x;
        __syncthreads();
    }
    partoff[t] = sh[t] - val;  // exclusive
}

__global__ __launch_bounds__(256) void scan3(const int* __restrict__ rex,
                                             const int* __restrict__ partoff,
                                             const int* __restrict__ cnt,
                                             int* __restrict__ row_start,
                                             int* __restrict__ cursor,
                                             float* __restrict__ dinv) {
    int i = blockIdx.x * 256 + threadIdx.x;
    if (i < NN) {
        row_start[i] = rex[i] + partoff[i >> 8];
        cursor[i] = 0;
        dinv[i] = rsqrtf(1.0f + (float)cnt[i]);
        if (i == 0) row_start[NN] = NE;
    }
}

__global__ __launch_bounds__(256) void scatter_kernel(const int* __restrict__ src,
                                                      const int* __restrict__ dst,
                                                      const int* __restrict__ row_start,
                                                      int* __restrict__ cursor,
                                                      int* __restrict__ sorted_src) {
    int e = blockIdx.x * 256 + threadIdx.x;
    if (e < NE) {
        int d = dst[e];
        int pos = atomicAdd(&cursor[d], 1);
        sorted_src[row_start[d] + pos] = src[e];
    }
}

// ---------------- GEMMs: register-blocked, write hs = bf16(dinv * (x@W)) -------
// tile 64 nodes x 64 feats, thread = 4 nodes x 4 feats
__global__ __launch_bounds__(256) void gemm_128_64_v2(const float* __restrict__ x,
                                                      const float* __restrict__ W,
                                                      const float* __restrict__ dinv,
                                                      unsigned short* __restrict__ hs) {
    __shared__ float xs[64][132];   // pad 132: bank-quad = (r + k/4) % 8 -> 2-way max
    int tid = threadIdx.x;
    int bn = blockIdx.x * 64;
    for (int id = tid; id < 64 * 33; id += 256) {
        int r = id / 33, c4 = id - r * 33;
        int n = bn + r; if (n >= NN) n = NN - 1;
        float4 v = make_float4(0.f, 0.f, 0.f, 0.f);
        if (c4 < 32) v = *(const float4*)(x + (size_t)n * 128 + c4 * 4);
        *(float4*)&xs[r][c4 * 4] = v;
    }
    __syncthreads();
    int tn = tid >> 4, tf = tid & 15;
    int f0 = tf * 4;
    float4 acc[4] = {{0,0,0,0},{0,0,0,0},{0,0,0,0},{0,0,0,0}};
#pragma unroll
    for (int k = 0; k < 128; k += 4) {
        float4 w0 = *(const float4*)(W + (k + 0) * 64 + f0);
        float4 w1 = *(const float4*)(W + (k + 1) * 64 + f0);
        float4 w2 = *(const float4*)(W + (k + 2) * 64 + f0);
        float4 w3 = *(const float4*)(W + (k + 3) * 64 + f0);
#pragma unroll
        for (int i = 0; i < 4; ++i) {
            float4 xa = *(const float4*)&xs[tn * 4 + i][k];
            fma4(acc[i], xa.x, w0); fma4(acc[i], xa.y, w1);
            fma4(acc[i], xa.z, w2); fma4(acc[i], xa.w, w3);
        }
    }
#pragma unroll
    for (int i = 0; i < 4; ++i) {
        int n = bn + tn * 4 + i;
        if (n < NN) {
            float di = dinv[n];
            ushort4 u;
            u.x = f2bf(acc[i].x * di); u.y = f2bf(acc[i].y * di);
            u.z = f2bf(acc[i].z * di); u.w = f2bf(acc[i].w * di);
            *(ushort4*)(hs + (size_t)n * 64 + f0) = u;
        }
    }
}

__global__ __launch_bounds__(256) void gemm_64_64_v2(const float* __restrict__ x,
                                                     const float* __restrict__ W,
                                                     const float* __restrict__ dinv,
                                                     unsigned short* __restrict__ hs) {
    __shared__ float xs[64][68];    // pad 68: quad = (r + k/4) % 8 -> 2-way max
    int tid = threadIdx.x;
    int bn = blockIdx.x * 64;
    for (int id = tid; id < 64 * 17; id += 256) {
        int r = id / 17, c4 = id - r * 17;
        int n = bn + r; if (n >= NN) n = NN - 1;
        float4 v = make_float4(0.f, 0.f, 0.f, 0.f);
        if (c4 < 16) v = *(const float4*)(x + (size_t)n * 64 + c4 * 4);
        *(float4*)&xs[r][c4 * 4] = v;
    }
    __syncthreads();
    int tn = tid >> 4, tf = tid & 15;
    int f0 = tf * 4;
    float4 acc[4] = {{0,0,0,0},{0,0,0,0},{0,0,0,0},{0,0,0,0}};
#pragma unroll
    for (int k = 0; k < 64; k += 4) {
        float4 w0 = *(const float4*)(W + (k + 0) * 64 + f0);
        float4 w1 = *(const float4*)(W + (k + 1) * 64 + f0);
        float4 w2 = *(const float4*)(W + (k + 2) * 64 + f0);
        float4 w3 = *(const float4*)(W + (k + 3) * 64 + f0);
#pragma unroll
        for (int i = 0; i < 4; ++i) {
            float4 xa = *(const float4*)&xs[tn * 4 + i][k];
            fma4(acc[i], xa.x, w0); fma4(acc[i], xa.y, w1);
            fma4(acc[i], xa.z, w2); fma4(acc[i], xa.w, w3);
        }
    }
#pragma unroll
    for (int i = 0; i < 4; ++i) {
        int n = bn + tn * 4 + i;
        if (n < NN) {
            float di = dinv[n];
            ushort4 u;
            u.x = f2bf(acc[i].x * di); u.y = f2bf(acc[i].y * di);
            u.z = f2bf(acc[i].z * di); u.w = f2bf(acc[i].w * di);
            *(ushort4*)(hs + (size_t)n * 64 + f0) = u;
        }
    }
}

// tile 128 nodes x 16 feats, thread = 4 nodes x 2 feats
__global__ __launch_bounds__(256) void gemm_64_16_v2(const float* __restrict__ x,
                                                     const float* __restrict__ W,
                                                     const float* __restrict__ dinv,
                                                     unsigned short* __restrict__ hs) {
    __shared__ float xs[128][68];
    int tid = threadIdx.x;
    int bn = blockIdx.x * 128;
    for (int id = tid; id < 128 * 17; id += 256) {
        int r = id / 17, c4 = id - r * 17;
        int n = bn + r; if (n >= NN) n = NN - 1;
        float4 v = make_float4(0.f, 0.f, 0.f, 0.f);
        if (c4 < 16) v = *(const float4*)(x + (size_t)n * 64 + c4 * 4);
        *(float4*)&xs[r][c4 * 4] = v;
    }
    __syncthreads();
    int tn = tid >> 3, tf = tid & 7;
    int f0 = tf * 2;
    float2 acc[4] = {{0,0},{0,0},{0,0},{0,0}};
#pragma unroll
    for (int k = 0; k < 64; k += 4) {
        float2 w0 = *(const float2*)(W + (k + 0) * 16 + f0);
        float2 w1 = *(const float2*)(W + (k + 1) * 16 + f0);
        float2 w2 = *(const float2*)(W + (k + 2) * 16 + f0);
        float2 w3 = *(const float2*)(W + (k + 3) * 16 + f0);
#pragma unroll
        for (int i = 0; i < 4; ++i) {
            float4 xa = *(const float4*)&xs[tn * 4 + i][k];
            fma2(acc[i], xa.x, w0); fma2(acc[i], xa.y, w1);
            fma2(acc[i], xa.z, w2); fma2(acc[i], xa.w, w3);
        }
    }
#pragma unroll
    for (int i = 0; i < 4; ++i) {
        int n = bn + tn * 4 + i;
        if (n < NN) {
            float di = dinv[n];
            ushort2 u;
            u.x = f2bf(acc[i].x * di); u.y = f2bf(acc[i].y * di);
            *(ushort2*)(hs + (size_t)n * 16 + f0) = u;
        }
    }
}

// ---------------- CSR aggregation (bf16 gather, fp32 accum, fused epilogue) ----
__global__ __launch_bounds__(256) void csr_agg64_bn_relu(const int* __restrict__ rs,
                                                         const int* __restrict__ ss,
                                                         const unsigned short* __restrict__ hs,
                                                         const float* __restrict__ dinv,
                                                         const float* __restrict__ b,
                                                         const float* __restrict__ g,
                                                         const float* __restrict__ be,
                                                         const float* __restrict__ m,
                                                         const float* __restrict__ v,
                                                         float* __restrict__ out) {
    int lane = threadIdx.x & 63;
    int r = blockIdx.x * 4 + (threadIdx.x >> 6);
    int e0 = rs[r], e1 = rs[r + 1];
    float a0 = bf2f(hs[(size_t)r * 64 + lane]);  // self loop
    float a1 = 0.f, a2 = 0.f, a3 = 0.f;
    for (int base = e0; base < e1; base += 64) {
        int nb = e1 - base; if (nb > 64) nb = 64;
        int sidx = (lane < nb) ? ss[base + lane] : 0;
        int j = 0;
        for (; j + 4 <= nb; j += 4) {
            int s0 = __shfl(sidx, j),     s1 = __shfl(sidx, j + 1);
            int s2 = __shfl(sidx, j + 2), s3 = __shfl(sidx, j + 3);
            a0 += bf2f(hs[(size_t)s0 * 64 + lane]);
            a1 += bf2f(hs[(size_t)s1 * 64 + lane]);
            a2 += bf2f(hs[(size_t)s2 * 64 + lane]);
            a3 += bf2f(hs[(size_t)s3 * 64 + lane]);
        }
        for (; j < nb; ++j)
            a0 += bf2f(hs[(size_t)__shfl(sidx, j) * 64 + lane]);
    }
    float acc = (a0 + a1) + (a2 + a3);
    float h = dinv[r] * acc + b[lane];
    h = g[lane] * (h - m[lane]) * rsqrtf(v[lane] + EPSBN) + be[lane];
    out[(size_t)r * 64 + lane] = fmaxf(h, 0.f);
}

__global__ __launch_bounds__(256) void csr_agg16_sigmoid(const int* __restrict__ rs,
                                                         const int* __restrict__ ss,
                                                         const unsigned short* __restrict__ hs,
                                                         const float* __restrict__ dinv,
                                                         const float* __restrict__ b,
                                                         float* __restrict__ out) {
    int lane = threadIdx.x & 63;
    int wid = blockIdx.x * 4 + (threadIdx.x >> 6);
    int grp = lane >> 4, fl = lane & 15;
    int r = wid * 4 + grp;
    int e0 = rs[r], e1 = rs[r + 1];
    float a0 = bf2f(hs[(size_t)r * 16 + fl]);  // self loop
    float a1 = 0.f, a2 = 0.f, a3 = 0.f;
    for (int base = e0; base < e1; base += 16) {
        int nb = e1 - base; if (nb > 16) nb = 16;
        int sidx = (fl < nb) ? ss[base + fl] : 0;
        int j = 0;
        for (; j + 4 <= nb; j += 4) {
            int s0 = __shfl(sidx, grp * 16 + j),     s1 = __shfl(sidx, grp * 16 + j + 1);
            int s2 = __shfl(sidx, grp * 16 + j + 2), s3 = __shfl(sidx, grp * 16 + j + 3);
            a0 += bf2f(hs[(size_t)s0 * 16 + fl]);
            a1 += bf2f(hs[(size_t)s1 * 16 + fl]);
            a2 += bf2f(hs[(size_t)s2 * 16 + fl]);
            a3 += bf2f(hs[(size_t)s3 * 16 + fl]);
        }
        for (; j < nb; ++j)
            a0 += bf2f(hs[(size_t)__shfl(sidx, grp * 16 + j) * 16 + fl]);
    }
    float acc = (a0 + a1) + (a2 + a3);
    float h = dinv[r] * acc + b[fl];
    out[(size_t)r * 16 + fl] = 1.0f / (1.0f + expf(-h));
}

extern "C" void kernel_launch(void* const* d_in, const int* in_sizes, int n_in,
                              void* d_out, int out_size, void* d_ws, size_t ws_size,
                              hipStream_t stream) {
    const float* x   = (const float*)d_in[0];
    const int*   ei  = (const int*)d_in[1];   // [2, E]: src = ei, dst = ei + NE
    const float* W1  = (const float*)d_in[2];
    const float* b1  = (const float*)d_in[3];
    const float* W2  = (const float*)d_in[4];
    const float* b2  = (const float*)d_in[5];
    const float* W3  = (const float*)d_in[6];
    const float* b3  = (const float*)d_in[7];
    const float* g1  = (const float*)d_in[8];
    const float* be1 = (const float*)d_in[9];
    const float* m1  = (const float*)d_in[10];
    const float* v1  = (const float*)d_in[11];
    const float* g2  = (const float*)d_in[12];
    const float* be2 = (const float*)d_in[13];
    const float* m2  = (const float*)d_in[14];
    const float* v2  = (const float*)d_in[15];
    float* out = (float*)d_out;

    const int* srcp = ei;
    const int* dstp = ei + NE;

    // workspace layout
    float* dinv = (float*)d_ws;                          // NN
    float* A    = dinv + NN;                             // NN*64 f32 activations
    unsigned short* Bh = (unsigned short*)(A + (size_t)NN * 64);  // NN*64 bf16 hs
    int* cnt        = (int*)(Bh + (size_t)NN * 64);      // NN
    int* rex        = cnt + NN;                          // NN
    int* row_start  = rex + NN;                          // NN+1
    int* cursor     = row_start + NN + 2;                // NN
    int* part       = cursor + NN;                       // 512
    int* partoff    = part + 512;                        // 512
    int* sorted_src = partoff + 512;                     // NE

    dim3 blk(256);
    int gN    = (NN + 255) / 256;    // 391
    int gE    = (NE + 255) / 256;    // 6250
    int gG1   = (NN + 63) / 64;      // 1563
    int gG3   = (NN + 127) / 128;    // 782
    int gA64  = NN / 4;              // 25000
    int gA16  = NN / 16;             // 6250

    // CSR build
    zero_cnt<<<gN, blk, 0, stream>>>(cnt);
    hist_kernel<<<gE, blk, 0, stream>>>(dstp, cnt);
    scan1<<<gN, blk, 0, stream>>>(cnt, rex, part);
    scan2<<<1, 512, 0, stream>>>(part, partoff);
    scan3<<<gN, blk, 0, stream>>>(rex, partoff, cnt, row_start, cursor, dinv);
    scatter_kernel<<<gE, blk, 0, stream>>>(srcp, dstp, row_start, cursor, sorted_src);

    // layer 1
    gemm_128_64_v2<<<gG1, blk, 0, stream>>>(x, W1, dinv, Bh);
    csr_agg64_bn_relu<<<gA64, blk, 0, stream>>>(row_start, sorted_src, Bh, dinv,
                                                b1, g1, be1, m1, v1, A);
    // layer 2
    gemm_64_64_v2<<<gG1, blk, 0, stream>>>(A, W2, dinv, Bh);
    csr_agg64_bn_relu<<<gA64, blk, 0, stream>>>(row_start, sorted_src, Bh, dinv,
                                                b2, g2, be2, m2, v2, A);
    // layer 3
    gemm_64_16_v2<<<gG3, blk, 0, stream>>>(A, W3, dinv, Bh);
    csr_agg16_sigmoid<<<gA16, blk, 0, stream>>>(row_start, sorted_src, Bh, dinv, b3, out);
}

// Round 4
// 476.345 us; speedup vs baseline: 2.7362x; 2.7362x over previous
//
#include <hip/hip_runtime.h>
#include <math.h>

#define NN 100000
#define NE 1600000
#define EPSBN 1e-5f
#define NB_SCAN 391   // ceil(NN/256)

// ---------------- bf16 helpers ----------------
static __device__ __forceinline__ unsigned short f2bf(float f) {
    unsigned int u = __float_as_uint(f);
    u += 0x7fffu + ((u >> 16) & 1u);   // round-to-nearest-even
    return (unsigned short)(u >> 16);
}
static __device__ __forceinline__ float bf2f(unsigned short s) {
    return __uint_as_float(((unsigned int)s) << 16);
}
static __device__ __forceinline__ void fma4(float4& a, float s, const float4& w) {
    a.x = fmaf(s, w.x, a.x); a.y = fmaf(s, w.y, a.y);
    a.z = fmaf(s, w.z, a.z); a.w = fmaf(s, w.w, a.w);
}
static __device__ __forceinline__ void fma2(float2& a, float s, const float2& w) {
    a.x = fmaf(s, w.x, a.x); a.y = fmaf(s, w.y, a.y);
}

// ---------------- CSR build ----------------
__global__ __launch_bounds__(256) void zero_cnt(int* __restrict__ cnt) {
    int i = blockIdx.x * 256 + threadIdx.x;
    if (i < NN) cnt[i] = 0;
}

__global__ __launch_bounds__(256) void hist_kernel(const int* __restrict__ dst,
                                                   int* __restrict__ cnt) {
    int e = blockIdx.x * 256 + threadIdx.x;
    if (e < NE) atomicAdd(&cnt[dst[e]], 1);
}

__global__ __launch_bounds__(256) void scan1(const int* __restrict__ cnt,
                                             int* __restrict__ rex,
                                             int* __restrict__ part) {
    __shared__ int sh[256];
    int t = threadIdx.x;
    int i = blockIdx.x * 256 + t;
    int val = (i < NN) ? cnt[i] : 0;
    sh[t] = val;
    __syncthreads();
    for (int off = 1; off < 256; off <<= 1) {
        int x = (t >= off) ? sh[t - off] : 0;
        __syncthreads();
        sh[t] += x;
        __syncthreads();
    }
    if (i < NN) rex[i] = sh[t] - val;
    if (t == 255) part[blockIdx.x] = sh[255];
}

__global__ __launch_bounds__(512) void scan2(const int* __restrict__ part,
                                             int* __restrict__ partoff) {
    __shared__ int sh[512];
    int t = threadIdx.x;
    int val = (t < NB_SCAN) ? part[t] : 0;
    sh[t] = val;
    __syncthreads();
    for (int off = 1; off < 512; off <<= 1) {
        int x = (t >= off) ? sh[t - off] : 0;
        __syncthreads();
        sh[t] += x;
        __syncthreads();
    }
    partoff[t] = sh[t] - val;  // exclusive
}

__global__ __launch_bounds__(256) void scan3(const int* __restrict__ rex,
                                             const int* __restrict__ partoff,
                                             const int* __restrict__ cnt,
                                             int* __restrict__ row_start,
                                             int* __restrict__ cursor,
                                             float* __restrict__ dinv) {
    int i = blockIdx.x * 256 + threadIdx.x;
    if (i < NN) {
        row_start[i] = rex[i] + partoff[i >> 8];
        cursor[i] = 0;
        dinv[i] = rsqrtf(1.0f + (float)cnt[i]);
        if (i == 0) row_start[NN] = NE;
    }
}

__global__ __launch_bounds__(256) void scatter_kernel(const int* __restrict__ src,
                                                      const int* __restrict__ dst,
                                                      const int* __restrict__ row_start,
                                                      int* __restrict__ cursor,
                                                      int* __restrict__ sorted_src) {
    int e = blockIdx.x * 256 + threadIdx.x;
    if (e < NE) {
        int d = dst[e];
        int pos = atomicAdd(&cursor[d], 1);
        sorted_src[row_start[d] + pos] = src[e];
    }
}

// ---------------- GEMMs: reg-blocked 4x4, W staged in LDS, unroll capped ------
// tile 64 nodes x 64 feats, thread = 4 nodes x 4 feats
__global__ __launch_bounds__(256) void gemm_128_64_v3(const float* __restrict__ x,
                                                      const float* __restrict__ W,
                                                      const float* __restrict__ dinv,
                                                      unsigned short* __restrict__ hs) {
    __shared__ float xs[64][132];   // pad: quad = (r + k/4) % 8 -> 2-way max (free)
    __shared__ float ws[128][64];   // 32 KB
    int tid = threadIdx.x;
    int bn = blockIdx.x * 64;
    for (int id = tid; id < 2048; id += 256) {          // W: 2048 float4
        int r = id >> 4, c4 = id & 15;
        *(float4*)&ws[r][c4 * 4] = *(const float4*)(W + r * 64 + c4 * 4);
    }
    for (int id = tid; id < 64 * 33; id += 256) {       // x tile
        int r = id / 33, c4 = id - r * 33;
        int n = bn + r; if (n >= NN) n = NN - 1;
        float4 v = make_float4(0.f, 0.f, 0.f, 0.f);
        if (c4 < 32) v = *(const float4*)(x + (size_t)n * 128 + c4 * 4);
        *(float4*)&xs[r][c4 * 4] = v;
    }
    __syncthreads();
    int tn = tid >> 4, tf = tid & 15;
    int f0 = tf * 4;
    float4 acc[4] = {{0,0,0,0},{0,0,0,0},{0,0,0,0},{0,0,0,0}};
#pragma unroll 2
    for (int k = 0; k < 128; k += 4) {
        float4 w0 = *(const float4*)&ws[k + 0][f0];
        float4 w1 = *(const float4*)&ws[k + 1][f0];
        float4 w2 = *(const float4*)&ws[k + 2][f0];
        float4 w3 = *(const float4*)&ws[k + 3][f0];
#pragma unroll
        for (int i = 0; i < 4; ++i) {
            float4 xa = *(const float4*)&xs[tn * 4 + i][k];
            fma4(acc[i], xa.x, w0); fma4(acc[i], xa.y, w1);
            fma4(acc[i], xa.z, w2); fma4(acc[i], xa.w, w3);
        }
    }
#pragma unroll
    for (int i = 0; i < 4; ++i) {
        int n = bn + tn * 4 + i;
        if (n < NN) {
            float di = dinv[n];
            ushort4 u;
            u.x = f2bf(acc[i].x * di); u.y = f2bf(acc[i].y * di);
            u.z = f2bf(acc[i].z * di); u.w = f2bf(acc[i].w * di);
            *(ushort4*)(hs + (size_t)n * 64 + f0) = u;
        }
    }
}

__global__ __launch_bounds__(256) void gemm_64_64_v3(const float* __restrict__ x,
                                                     const float* __restrict__ W,
                                                     const float* __restrict__ dinv,
                                                     unsigned short* __restrict__ hs) {
    __shared__ float xs[64][68];
    __shared__ float ws[64][64];   // 16 KB
    int tid = threadIdx.x;
    int bn = blockIdx.x * 64;
    for (int id = tid; id < 1024; id += 256) {          // W: 1024 float4
        int r = id >> 4, c4 = id & 15;
        *(float4*)&ws[r][c4 * 4] = *(const float4*)(W + r * 64 + c4 * 4);
    }
    for (int id = tid; id < 64 * 17; id += 256) {
        int r = id / 17, c4 = id - r * 17;
        int n = bn + r; if (n >= NN) n = NN - 1;
        float4 v = make_float4(0.f, 0.f, 0.f, 0.f);
        if (c4 < 16) v = *(const float4*)(x + (size_t)n * 64 + c4 * 4);
        *(float4*)&xs[r][c4 * 4] = v;
    }
    __syncthreads();
    int tn = tid >> 4, tf = tid & 15;
    int f0 = tf * 4;
    float4 acc[4] = {{0,0,0,0},{0,0,0,0},{0,0,0,0},{0,0,0,0}};
#pragma unroll 2
    for (int k = 0; k < 64; k += 4) {
        float4 w0 = *(const float4*)&ws[k + 0][f0];
        float4 w1 = *(const float4*)&ws[k + 1][f0];
        float4 w2 = *(const float4*)&ws[k + 2][f0];
        float4 w3 = *(const float4*)&ws[k + 3][f0];
#pragma unroll
        for (int i = 0; i < 4; ++i) {
            float4 xa = *(const float4*)&xs[tn * 4 + i][k];
            fma4(acc[i], xa.x, w0); fma4(acc[i], xa.y, w1);
            fma4(acc[i], xa.z, w2); fma4(acc[i], xa.w, w3);
        }
    }
#pragma unroll
    for (int i = 0; i < 4; ++i) {
        int n = bn + tn * 4 + i;
        if (n < NN) {
            float di = dinv[n];
            ushort4 u;
            u.x = f2bf(acc[i].x * di); u.y = f2bf(acc[i].y * di);
            u.z = f2bf(acc[i].z * di); u.w = f2bf(acc[i].w * di);
            *(ushort4*)(hs + (size_t)n * 64 + f0) = u;
        }
    }
}

// tile 128 nodes x 16 feats, thread = 4 nodes x 2 feats
__global__ __launch_bounds__(256) void gemm_64_16_v3(const float* __restrict__ x,
                                                     const float* __restrict__ W,
                                                     const float* __restrict__ dinv,
                                                     unsigned short* __restrict__ hs) {
    __shared__ float xs[128][68];
    __shared__ float ws[64][16];   // 4 KB
    int tid = threadIdx.x;
    int bn = blockIdx.x * 128;
    for (int id = tid; id < 256; id += 256) {           // W: 256 float4
        int r = id >> 2, c4 = id & 3;
        *(float4*)&ws[r][c4 * 4] = *(const float4*)(W + r * 16 + c4 * 4);
    }
    for (int id = tid; id < 128 * 17; id += 256) {
        int r = id / 17, c4 = id - r * 17;
        int n = bn + r; if (n >= NN) n = NN - 1;
        float4 v = make_float4(0.f, 0.f, 0.f, 0.f);
        if (c4 < 16) v = *(const float4*)(x + (size_t)n * 64 + c4 * 4);
        *(float4*)&xs[r][c4 * 4] = v;
    }
    __syncthreads();
    int tn = tid >> 3, tf = tid & 7;
    int f0 = tf * 2;
    float2 acc[4] = {{0,0},{0,0},{0,0},{0,0}};
#pragma unroll 2
    for (int k = 0; k < 64; k += 4) {
        float2 w0 = *(const float2*)&ws[k + 0][f0];
        float2 w1 = *(const float2*)&ws[k + 1][f0];
        float2 w2 = *(const float2*)&ws[k + 2][f0];
        float2 w3 = *(const float2*)&ws[k + 3][f0];
#pragma unroll
        for (int i = 0; i < 4; ++i) {
            float4 xa = *(const float4*)&xs[tn * 4 + i][k];
            fma2(acc[i], xa.x, w0); fma2(acc[i], xa.y, w1);
            fma2(acc[i], xa.z, w2); fma2(acc[i], xa.w, w3);
        }
    }
#pragma unroll
    for (int i = 0; i < 4; ++i) {
        int n = bn + tn * 4 + i;
        if (n < NN) {
            float di = dinv[n];
            ushort2 u;
            u.x = f2bf(acc[i].x * di); u.y = f2bf(acc[i].y * di);
            *(ushort2*)(hs + (size_t)n * 16 + f0) = u;
        }
    }
}

// ---------------- CSR aggregation (bf16 gather, fp32 accum, fused epilogue) ----
__global__ __launch_bounds__(256) void csr_agg64_bn_relu(const int* __restrict__ rs,
                                                         const int* __restrict__ ss,
                                                         const unsigned short* __restrict__ hs,
                                                         const float* __restrict__ dinv,
                                                         const float* __restrict__ b,
                                                         const float* __restrict__ g,
                                                         const float* __restrict__ be,
                                                         const float* __restrict__ m,
                                                         const float* __restrict__ v,
                                                         float* __restrict__ out) {
    int lane = threadIdx.x & 63;
    int r = blockIdx.x * 4 + (threadIdx.x >> 6);
    int e0 = rs[r], e1 = rs[r + 1];
    float a0 = bf2f(hs[(size_t)r * 64 + lane]);  // self loop
    float a1 = 0.f, a2 = 0.f, a3 = 0.f;
    for (int base = e0; base < e1; base += 64) {
        int nb = e1 - base; if (nb > 64) nb = 64;
        int sidx = (lane < nb) ? ss[base + lane] : 0;
        int j = 0;
        for (; j + 4 <= nb; j += 4) {
            int s0 = __shfl(sidx, j),     s1 = __shfl(sidx, j + 1);
            int s2 = __shfl(sidx, j + 2), s3 = __shfl(sidx, j + 3);
            a0 += bf2f(hs[(size_t)s0 * 64 + lane]);
            a1 += bf2f(hs[(size_t)s1 * 64 + lane]);
            a2 += bf2f(hs[(size_t)s2 * 64 + lane]);
            a3 += bf2f(hs[(size_t)s3 * 64 + lane]);
        }
        for (; j < nb; ++j)
            a0 += bf2f(hs[(size_t)__shfl(sidx, j) * 64 + lane]);
    }
    float acc = (a0 + a1) + (a2 + a3);
    float h = dinv[r] * acc + b[lane];
    h = g[lane] * (h - m[lane]) * rsqrtf(v[lane] + EPSBN) + be[lane];
    out[(size_t)r * 64 + lane] = fmaxf(h, 0.f);
}

__global__ __launch_bounds__(256) void csr_agg16_sigmoid(const int* __restrict__ rs,
                                                         const int* __restrict__ ss,
                                                         const unsigned short* __restrict__ hs,
                                                         const float* __restrict__ dinv,
                                                         const float* __restrict__ b,
                                                         float* __restrict__ out) {
    int lane = threadIdx.x & 63;
    int wid = blockIdx.x * 4 + (threadIdx.x >> 6);
    int grp = lane >> 4, fl = lane & 15;
    int r = wid * 4 + grp;
    int e0 = rs[r], e1 = rs[r + 1];
    float a0 = bf2f(hs[(size_t)r * 16 + fl]);  // self loop
    float a1 = 0.f, a2 = 0.f, a3 = 0.f;
    for (int base = e0; base < e1; base += 16) {
        int nb = e1 - base; if (nb > 16) nb = 16;
        int sidx = (fl < nb) ? ss[base + fl] : 0;
        int j = 0;
        for (; j + 4 <= nb; j += 4) {
            int s0 = __shfl(sidx, grp * 16 + j),     s1 = __shfl(sidx, grp * 16 + j + 1);
            int s2 = __shfl(sidx, grp * 16 + j + 2), s3 = __shfl(sidx, grp * 16 + j + 3);
            a0 += bf2f(hs[(size_t)s0 * 16 + fl]);
            a1 += bf2f(hs[(size_t)s1 * 16 + fl]);
            a2 += bf2f(hs[(size_t)s2 * 16 + fl]);
            a3 += bf2f(hs[(size_t)s3 * 16 + fl]);
        }
        for (; j < nb; ++j)
            a0 += bf2f(hs[(size_t)__shfl(sidx, grp * 16 + j) * 16 + fl]);
    }
    float acc = (a0 + a1) + (a2 + a3);
    float h = dinv[r] * acc + b[fl];
    out[(size_t)r * 16 + fl] = 1.0f / (1.0f + expf(-h));
}

extern "C" void kernel_launch(void* const* d_in, const int* in_sizes, int n_in,
                              void* d_out, int out_size, void* d_ws, size_t ws_size,
                              hipStream_t stream) {
    const float* x   = (const float*)d_in[0];
    const int*   ei  = (const int*)d_in[1];   // [2, E]: src = ei, dst = ei + NE
    const float* W1  = (const float*)d_in[2];
    const float* b1  = (const float*)d_in[3];
    const float* W2  = (const float*)d_in[4];
    const float* b2  = (const float*)d_in[5];
    const float* W3  = (const float*)d_in[6];
    const float* b3  = (const float*)d_in[7];
    const float* g1  = (const float*)d_in[8];
    const float* be1 = (const float*)d_in[9];
    const float* m1  = (const float*)d_in[10];
    const float* v1  = (const float*)d_in[11];
    const float* g2  = (const float*)d_in[12];
    const float* be2 = (const float*)d_in[13];
    const float* m2  = (const float*)d_in[14];
    const float* v2  = (const float*)d_in[15];
    float* out = (float*)d_out;

    const int* srcp = ei;
    const int* dstp = ei + NE;

    // workspace layout
    float* dinv = (float*)d_ws;                          // NN
    float* A    = dinv + NN;                             // NN*64 f32 activations
    unsigned short* Bh = (unsigned short*)(A + (size_t)NN * 64);  // NN*64 bf16 hs
    int* cnt        = (int*)(Bh + (size_t)NN * 64);      // NN
    int* rex        = cnt + NN;                          // NN
    int* row_start  = rex + NN;                          // NN+1
    int* cursor     = row_start + NN + 2;                // NN
    int* part       = cursor + NN;                       // 512
    int* partoff    = part + 512;                        // 512
    int* sorted_src = partoff + 512;                     // NE

    dim3 blk(256);
    int gN    = (NN + 255) / 256;    // 391
    int gE    = (NE + 255) / 256;    // 6250
    int gG1   = (NN + 63) / 64;      // 1563
    int gG3   = (NN + 127) / 128;    // 782
    int gA64  = NN / 4;              // 25000
    int gA16  = NN / 16;             // 6250

    // CSR build
    zero_cnt<<<gN, blk, 0, stream>>>(cnt);
    hist_kernel<<<gE, blk, 0, stream>>>(dstp, cnt);
    scan1<<<gN, blk, 0, stream>>>(cnt, rex, part);
    scan2<<<1, 512, 0, stream>>>(part, partoff);
    scan3<<<gN, blk, 0, stream>>>(rex, partoff, cnt, row_start, cursor, dinv);
    scatter_kernel<<<gE, blk, 0, stream>>>(srcp, dstp, row_start, cursor, sorted_src);

    // layer 1
    gemm_128_64_v3<<<gG1, blk, 0, stream>>>(x, W1, dinv, Bh);
    csr_agg64_bn_relu<<<gA64, blk, 0, stream>>>(row_start, sorted_src, Bh, dinv,
                                                b1, g1, be1, m1, v1, A);
    // layer 2
    gemm_64_64_v3<<<gG1, blk, 0, stream>>>(A, W2, dinv, Bh);
    csr_agg64_bn_relu<<<gA64, blk, 0, stream>>>(row_start, sorted_src, Bh, dinv,
                                                b2, g2, be2, m2, v2, A);
    // layer 3
    gemm_64_16_v3<<<gG3, blk, 0, stream>>>(A, W3, dinv, Bh);
    csr_agg16_sigmoid<<<gA16, blk, 0, stream>>>(row_start, sorted_src, Bh, dinv, b3, out);
}

// Round 5
// 416.634 us; speedup vs baseline: 3.1283x; 1.1433x over previous
//
#include <hip/hip_runtime.h>
#include <math.h>

#define NN 100000
#define NE 1600000
#define EPSBN 1e-5f
#define NB_SCAN 391   // ceil(NN/256) == number of dst buckets (bucket = dst>>8)
#define NBUCK 391

// ---------------- bf16 helpers ----------------
static __device__ __forceinline__ unsigned short f2bf(float f) {
    unsigned int u = __float_as_uint(f);
    u += 0x7fffu + ((u >> 16) & 1u);   // round-to-nearest-even
    return (unsigned short)(u >> 16);
}
static __device__ __forceinline__ float bf2f(unsigned short s) {
    return __uint_as_float(((unsigned int)s) << 16);
}
static __device__ __forceinline__ void fma4(float4& a, float s, const float4& w) {
    a.x = fmaf(s, w.x, a.x); a.y = fmaf(s, w.y, a.y);
    a.z = fmaf(s, w.z, a.z); a.w = fmaf(s, w.w, a.w);
}
static __device__ __forceinline__ void fma2(float2& a, float s, const float2& w) {
    a.x = fmaf(s, w.x, a.x); a.y = fmaf(s, w.y, a.y);
}

// ---------------- CSR build ----------------
__global__ __launch_bounds__(256) void zero_cnt(int* __restrict__ cnt) {
    int i = blockIdx.x * 256 + threadIdx.x;
    if (i < NN) cnt[i] = 0;
}

__global__ __launch_bounds__(256) void hist_kernel(const int* __restrict__ dst,
                                                   int* __restrict__ cnt) {
    int e = blockIdx.x * 256 + threadIdx.x;
    if (e < NE) atomicAdd(&cnt[dst[e]], 1);
}

// per-block exclusive scan; part[b] doubles as the bucket-b edge count
__global__ __launch_bounds__(256) void scan1(const int* __restrict__ cnt,
                                             int* __restrict__ rex,
                                             int* __restrict__ part) {
    __shared__ int sh[256];
    int t = threadIdx.x;
    int i = blockIdx.x * 256 + t;
    int val = (i < NN) ? cnt[i] : 0;
    sh[t] = val;
    __syncthreads();
    for (int off = 1; off < 256; off <<= 1) {
        int x = (t >= off) ? sh[t - off] : 0;
        __syncthreads();
        sh[t] += x;
        __syncthreads();
    }
    if (i < NN) rex[i] = sh[t] - val;
    if (t == 255) part[blockIdx.x] = sh[255];
}

// partoff[b] doubles as bucket base bb0[b]; partoff[NBUCK] == NE
__global__ __launch_bounds__(512) void scan2(const int* __restrict__ part,
                                             int* __restrict__ partoff) {
    __shared__ int sh[512];
    int t = threadIdx.x;
    int val = (t < NB_SCAN) ? part[t] : 0;
    sh[t] = val;
    __syncthreads();
    for (int off = 1; off < 512; off <<= 1) {
        int x = (t >= off) ? sh[t - off] : 0;
        __syncthreads();
        sh[t] += x;
        __syncthreads();
    }
    partoff[t] = sh[t] - val;  // exclusive
}

__global__ __launch_bounds__(256) void scan3(const int* __restrict__ rex,
                                             const int* __restrict__ partoff,
                                             const int* __restrict__ cnt,
                                             int* __restrict__ row_start,
                                             int* __restrict__ bcur,
                                             float* __restrict__ dinv) {
    int i = blockIdx.x * 256 + threadIdx.x;
    if (i < NN) {
        row_start[i] = rex[i] + partoff[i >> 8];
        dinv[i] = rsqrtf(1.0f + (float)cnt[i]);
        if (i == 0) row_start[NN] = NE;
    }
    if (i < 512) bcur[i] = 0;
}

// phase 1: radix-style binning by dst>>8. Per-block local hist + run reservation,
// so each (block,bucket) run is written contiguously by one block (XCD-local).
__global__ __launch_bounds__(256) void bin_kernel(const int* __restrict__ src,
                                                  const int* __restrict__ dst,
                                                  const int* __restrict__ bb0,
                                                  int* __restrict__ bcur,
                                                  unsigned int* __restrict__ bucketed) {
    __shared__ int lh[NBUCK];
    __shared__ int lbase[NBUCK];
    __shared__ int lcur[NBUCK];
    int t = threadIdx.x;
    for (int b = t; b < NBUCK; b += 256) lh[b] = 0;
    __syncthreads();
    int e0 = blockIdx.x * 4096;
#pragma unroll
    for (int i = 0; i < 16; ++i) {
        int e = e0 + i * 256 + t;
        if (e < NE) atomicAdd(&lh[dst[e] >> 8], 1);
    }
    __syncthreads();
    for (int b = t; b < NBUCK; b += 256) {
        lbase[b] = bb0[b] + atomicAdd(&bcur[b], lh[b]);
        lcur[b] = 0;
    }
    __syncthreads();
#pragma unroll
    for (int i = 0; i < 16; ++i) {
        int e = e0 + i * 256 + t;
        if (e < NE) {
            int d = dst[e], s = src[e];
            int b = d >> 8;
            int pos = lbase[b] + atomicAdd(&lcur[b], 1);
            bucketed[pos] = (unsigned int)s | ((unsigned int)(d & 255) << 24);
        }
    }
}

// phase 2: one block per bucket; cursor in LDS; writes confined to the bucket's
// contiguous sorted_src window (single block -> no cross-XCD line sharing).
__global__ __launch_bounds__(256) void fine_scatter(const unsigned int* __restrict__ bucketed,
                                                    const int* __restrict__ bb0,
                                                    const int* __restrict__ row_start,
                                                    int* __restrict__ sorted_src) {
    __shared__ int lcur[256];
    int b = blockIdx.x;
    int t = threadIdx.x;
    lcur[t] = 0;
    __syncthreads();
    int e0 = bb0[b], e1 = bb0[b + 1];
    for (int e = e0 + t; e < e1; e += 256) {
        unsigned int p = bucketed[e];
        int dl = (int)(p >> 24);
        int s  = (int)(p & 0xFFFFFFu);
        int pos = row_start[b * 256 + dl] + atomicAdd(&lcur[dl], 1);
        sorted_src[pos] = s;
    }
}

// ---------------- GEMMs: reg-blocked 4x4, W staged in LDS, unroll capped ------
__global__ __launch_bounds__(256) void gemm_128_64_v3(const float* __restrict__ x,
                                                      const float* __restrict__ W,
                                                      const float* __restrict__ dinv,
                                                      unsigned short* __restrict__ hs) {
    __shared__ float xs[64][132];
    __shared__ float ws[128][64];
    int tid = threadIdx.x;
    int bn = blockIdx.x * 64;
    for (int id = tid; id < 2048; id += 256) {
        int r = id >> 4, c4 = id & 15;
        *(float4*)&ws[r][c4 * 4] = *(const float4*)(W + r * 64 + c4 * 4);
    }
    for (int id = tid; id < 64 * 33; id += 256) {
        int r = id / 33, c4 = id - r * 33;
        int n = bn + r; if (n >= NN) n = NN - 1;
        float4 v = make_float4(0.f, 0.f, 0.f, 0.f);
        if (c4 < 32) v = *(const float4*)(x + (size_t)n * 128 + c4 * 4);
        *(float4*)&xs[r][c4 * 4] = v;
    }
    __syncthreads();
    int tn = tid >> 4, tf = tid & 15;
    int f0 = tf * 4;
    float4 acc[4] = {{0,0,0,0},{0,0,0,0},{0,0,0,0},{0,0,0,0}};
#pragma unroll 2
    for (int k = 0; k < 128; k += 4) {
        float4 w0 = *(const float4*)&ws[k + 0][f0];
        float4 w1 = *(const float4*)&ws[k + 1][f0];
        float4 w2 = *(const float4*)&ws[k + 2][f0];
        float4 w3 = *(const float4*)&ws[k + 3][f0];
#pragma unroll
        for (int i = 0; i < 4; ++i) {
            float4 xa = *(const float4*)&xs[tn * 4 + i][k];
            fma4(acc[i], xa.x, w0); fma4(acc[i], xa.y, w1);
            fma4(acc[i], xa.z, w2); fma4(acc[i], xa.w, w3);
        }
    }
#pragma unroll
    for (int i = 0; i < 4; ++i) {
        int n = bn + tn * 4 + i;
        if (n < NN) {
            float di = dinv[n];
            ushort4 u;
            u.x = f2bf(acc[i].x * di); u.y = f2bf(acc[i].y * di);
            u.z = f2bf(acc[i].z * di); u.w = f2bf(acc[i].w * di);
            *(ushort4*)(hs + (size_t)n * 64 + f0) = u;
        }
    }
}

__global__ __launch_bounds__(256) void gemm_64_64_v3(const float* __restrict__ x,
                                                     const float* __restrict__ W,
                                                     const float* __restrict__ dinv,
                                                     unsigned short* __restrict__ hs) {
    __shared__ float xs[64][68];
    __shared__ float ws[64][64];
    int tid = threadIdx.x;
    int bn = blockIdx.x * 64;
    for (int id = tid; id < 1024; id += 256) {
        int r = id >> 4, c4 = id & 15;
        *(float4*)&ws[r][c4 * 4] = *(const float4*)(W + r * 64 + c4 * 4);
    }
    for (int id = tid; id < 64 * 17; id += 256) {
        int r = id / 17, c4 = id - r * 17;
        int n = bn + r; if (n >= NN) n = NN - 1;
        float4 v = make_float4(0.f, 0.f, 0.f, 0.f);
        if (c4 < 16) v = *(const float4*)(x + (size_t)n * 64 + c4 * 4);
        *(float4*)&xs[r][c4 * 4] = v;
    }
    __syncthreads();
    int tn = tid >> 4, tf = tid & 15;
    int f0 = tf * 4;
    float4 acc[4] = {{0,0,0,0},{0,0,0,0},{0,0,0,0},{0,0,0,0}};
#pragma unroll 2
    for (int k = 0; k < 64; k += 4) {
        float4 w0 = *(const float4*)&ws[k + 0][f0];
        float4 w1 = *(const float4*)&ws[k + 1][f0];
        float4 w2 = *(const float4*)&ws[k + 2][f0];
        float4 w3 = *(const float4*)&ws[k + 3][f0];
#pragma unroll
        for (int i = 0; i < 4; ++i) {
            float4 xa = *(const float4*)&xs[tn * 4 + i][k];
            fma4(acc[i], xa.x, w0); fma4(acc[i], xa.y, w1);
            fma4(acc[i], xa.z, w2); fma4(acc[i], xa.w, w3);
        }
    }
#pragma unroll
    for (int i = 0; i < 4; ++i) {
        int n = bn + tn * 4 + i;
        if (n < NN) {
            float di = dinv[n];
            ushort4 u;
            u.x = f2bf(acc[i].x * di); u.y = f2bf(acc[i].y * di);
            u.z = f2bf(acc[i].z * di); u.w = f2bf(acc[i].w * di);
            *(ushort4*)(hs + (size_t)n * 64 + f0) = u;
        }
    }
}

__global__ __launch_bounds__(256) void gemm_64_16_v3(const float* __restrict__ x,
                                                     const float* __restrict__ W,
                                                     const float* __restrict__ dinv,
                                                     unsigned short* __restrict__ hs) {
    __shared__ float xs[128][68];
    __shared__ float ws[64][16];
    int tid = threadIdx.x;
    int bn = blockIdx.x * 128;
    for (int id = tid; id < 256; id += 256) {
        int r = id >> 2, c4 = id & 3;
        *(float4*)&ws[r][c4 * 4] = *(const float4*)(W + r * 16 + c4 * 4);
    }
    for (int id = tid; id < 128 * 17; id += 256) {
        int r = id / 17, c4 = id - r * 17;
        int n = bn + r; if (n >= NN) n = NN - 1;
        float4 v = make_float4(0.f, 0.f, 0.f, 0.f);
        if (c4 < 16) v = *(const float4*)(x + (size_t)n * 64 + c4 * 4);
        *(float4*)&xs[r][c4 * 4] = v;
    }
    __syncthreads();
    int tn = tid >> 3, tf = tid & 7;
    int f0 = tf * 2;
    float2 acc[4] = {{0,0},{0,0},{0,0},{0,0}};
#pragma unroll 2
    for (int k = 0; k < 64; k += 4) {
        float2 w0 = *(const float2*)&ws[k + 0][f0];
        float2 w1 = *(const float2*)&ws[k + 1][f0];
        float2 w2 = *(const float2*)&ws[k + 2][f0];
        float2 w3 = *(const float2*)&ws[k + 3][f0];
#pragma unroll
        for (int i = 0; i < 4; ++i) {
            float4 xa = *(const float4*)&xs[tn * 4 + i][k];
            fma2(acc[i], xa.x, w0); fma2(acc[i], xa.y, w1);
            fma2(acc[i], xa.z, w2); fma2(acc[i], xa.w, w3);
        }
    }
#pragma unroll
    for (int i = 0; i < 4; ++i) {
        int n = bn + tn * 4 + i;
        if (n < NN) {
            float di = dinv[n];
            ushort2 u;
            u.x = f2bf(acc[i].x * di); u.y = f2bf(acc[i].y * di);
            *(ushort2*)(hs + (size_t)n * 16 + f0) = u;
        }
    }
}

// ---------------- CSR aggregation (bf16 gather, fp32 accum, fused epilogue) ----
__global__ __launch_bounds__(256) void csr_agg64_bn_relu(const int* __restrict__ rs,
                                                         const int* __restrict__ ss,
                                                         const unsigned short* __restrict__ hs,
                                                         const float* __restrict__ dinv,
                                                         const float* __restrict__ b,
                                                         const float* __restrict__ g,
                                                         const float* __restrict__ be,
                                                         const float* __restrict__ m,
                                                         const float* __restrict__ v,
                                                         float* __restrict__ out) {
    int lane = threadIdx.x & 63;
    int r = blockIdx.x * 4 + (threadIdx.x >> 6);
    int e0 = rs[r], e1 = rs[r + 1];
    float a0 = bf2f(hs[(size_t)r * 64 + lane]);  // self loop
    float a1 = 0.f, a2 = 0.f, a3 = 0.f;
    for (int base = e0; base < e1; base += 64) {
        int nb = e1 - base; if (nb > 64) nb = 64;
        int sidx = (lane < nb) ? ss[base + lane] : 0;
        int j = 0;
        for (; j + 4 <= nb; j += 4) {
            int s0 = __shfl(sidx, j),     s1 = __shfl(sidx, j + 1);
            int s2 = __shfl(sidx, j + 2), s3 = __shfl(sidx, j + 3);
            a0 += bf2f(hs[(size_t)s0 * 64 + lane]);
            a1 += bf2f(hs[(size_t)s1 * 64 + lane]);
            a2 += bf2f(hs[(size_t)s2 * 64 + lane]);
            a3 += bf2f(hs[(size_t)s3 * 64 + lane]);
        }
        for (; j < nb; ++j)
            a0 += bf2f(hs[(size_t)__shfl(sidx, j) * 64 + lane]);
    }
    float acc = (a0 + a1) + (a2 + a3);
    float h = dinv[r] * acc + b[lane];
    h = g[lane] * (h - m[lane]) * rsqrtf(v[lane] + EPSBN) + be[lane];
    out[(size_t)r * 64 + lane] = fmaxf(h, 0.f);
}

__global__ __launch_bounds__(256) void csr_agg16_sigmoid(const int* __restrict__ rs,
                                                         const int* __restrict__ ss,
                                                         const unsigned short* __restrict__ hs,
                                                         const float* __restrict__ dinv,
                                                         const float* __restrict__ b,
                                                         float* __restrict__ out) {
    int lane = threadIdx.x & 63;
    int wid = blockIdx.x * 4 + (threadIdx.x >> 6);
    int grp = lane >> 4, fl = lane & 15;
    int r = wid * 4 + grp;
    int e0 = rs[r], e1 = rs[r + 1];
    float a0 = bf2f(hs[(size_t)r * 16 + fl]);  // self loop
    float a1 = 0.f, a2 = 0.f, a3 = 0.f;
    for (int base = e0; base < e1; base += 16) {
        int nb = e1 - base; if (nb > 16) nb = 16;
        int sidx = (fl < nb) ? ss[base + fl] : 0;
        int j = 0;
        for (; j + 4 <= nb; j += 4) {
            int s0 = __shfl(sidx, grp * 16 + j),     s1 = __shfl(sidx, grp * 16 + j + 1);
            int s2 = __shfl(sidx, grp * 16 + j + 2), s3 = __shfl(sidx, grp * 16 + j + 3);
            a0 += bf2f(hs[(size_t)s0 * 16 + fl]);
            a1 += bf2f(hs[(size_t)s1 * 16 + fl]);
            a2 += bf2f(hs[(size_t)s2 * 16 + fl]);
            a3 += bf2f(hs[(size_t)s3 * 16 + fl]);
        }
        for (; j < nb; ++j)
            a0 += bf2f(hs[(size_t)__shfl(sidx, grp * 16 + j) * 16 + fl]);
    }
    float acc = (a0 + a1) + (a2 + a3);
    float h = dinv[r] * acc + b[fl];
    out[(size_t)r * 16 + fl] = 1.0f / (1.0f + expf(-h));
}

extern "C" void kernel_launch(void* const* d_in, const int* in_sizes, int n_in,
                              void* d_out, int out_size, void* d_ws, size_t ws_size,
                              hipStream_t stream) {
    const float* x   = (const float*)d_in[0];
    const int*   ei  = (const int*)d_in[1];   // [2, E]: src = ei, dst = ei + NE
    const float* W1  = (const float*)d_in[2];
    const float* b1  = (const float*)d_in[3];
    const float* W2  = (const float*)d_in[4];
    const float* b2  = (const float*)d_in[5];
    const float* W3  = (const float*)d_in[6];
    const float* b3  = (const float*)d_in[7];
    const float* g1  = (const float*)d_in[8];
    const float* be1 = (const float*)d_in[9];
    const float* m1  = (const float*)d_in[10];
    const float* v1  = (const float*)d_in[11];
    const float* g2  = (const float*)d_in[12];
    const float* be2 = (const float*)d_in[13];
    const float* m2  = (const float*)d_in[14];
    const float* v2  = (const float*)d_in[15];
    float* out = (float*)d_out;

    const int* srcp = ei;
    const int* dstp = ei + NE;

    // workspace layout
    float* dinv = (float*)d_ws;                          // NN
    float* A    = dinv + NN;                             // NN*64 f32 activations
    unsigned short* Bh = (unsigned short*)(A + (size_t)NN * 64);  // NN*64 bf16 hs
    int* cnt        = (int*)(Bh + (size_t)NN * 64);      // NN
    int* rex        = cnt + NN;                          // NN
    int* row_start  = rex + NN;                          // NN+1
    int* bcur       = row_start + NN + 2;                // 512
    int* part       = bcur + 512;                        // 512
    int* partoff    = part + 512;                        // 512  (bucket bases bb0)
    int* sorted_src = partoff + 512;                     // NE
    unsigned int* bucketed = (unsigned int*)(sorted_src + NE);  // NE

    dim3 blk(256);
    int gN    = (NN + 255) / 256;    // 391
    int gE    = (NE + 255) / 256;    // 6250
    int gBIN  = (NE + 4095) / 4096;  // 391
    int gG1   = (NN + 63) / 64;      // 1563
    int gG3   = (NN + 127) / 128;    // 782
    int gA64  = NN / 4;              // 25000
    int gA16  = NN / 16;             // 6250

    // CSR build (two-phase radix by dst)
    zero_cnt<<<gN, blk, 0, stream>>>(cnt);
    hist_kernel<<<gE, blk, 0, stream>>>(dstp, cnt);
    scan1<<<gN, blk, 0, stream>>>(cnt, rex, part);
    scan2<<<1, 512, 0, stream>>>(part, partoff);
    scan3<<<gN, blk, 0, stream>>>(rex, partoff, cnt, row_start, bcur, dinv);
    bin_kernel<<<gBIN, blk, 0, stream>>>(srcp, dstp, partoff, bcur, bucketed);
    fine_scatter<<<NBUCK, blk, 0, stream>>>(bucketed, partoff, row_start, sorted_src);

    // layer 1
    gemm_128_64_v3<<<gG1, blk, 0, stream>>>(x, W1, dinv, Bh);
    csr_agg64_bn_relu<<<gA64, blk, 0, stream>>>(row_start, sorted_src, Bh, dinv,
                                                b1, g1, be1, m1, v1, A);
    // layer 2
    gemm_64_64_v3<<<gG1, blk, 0, stream>>>(A, W2, dinv, Bh);
    csr_agg64_bn_relu<<<gA64, blk, 0, stream>>>(row_start, sorted_src, Bh, dinv,
                                                b2, g2, be2, m2, v2, A);
    // layer 3
    gemm_64_16_v3<<<gG3, blk, 0, stream>>>(A, W3, dinv, Bh);
    csr_agg16_sigmoid<<<gA16, blk, 0, stream>>>(row_start, sorted_src, Bh, dinv, b3, out);
}

// Round 6
// 361.056 us; speedup vs baseline: 3.6098x; 1.1539x over previous
//
#include <hip/hip_runtime.h>
#include <math.h>

#define NN 100000
#define NE 1600000
#define EPSBN 1e-5f
#define NBUCK 391   // ceil(NN/256); bucket = dst>>8

// ---------------- bf16 helpers ----------------
static __device__ __forceinline__ unsigned short f2bf(float f) {
    unsigned int u = __float_as_uint(f);
    u += 0x7fffu + ((u >> 16) & 1u);   // round-to-nearest-even
    return (unsigned short)(u >> 16);
}
static __device__ __forceinline__ float bf2f(unsigned short s) {
    return __uint_as_float(((unsigned int)s) << 16);
}
static __device__ __forceinline__ void fma4(float4& a, float s, const float4& w) {
    a.x = fmaf(s, w.x, a.x); a.y = fmaf(s, w.y, a.y);
    a.z = fmaf(s, w.z, a.z); a.w = fmaf(s, w.w, a.w);
}
static __device__ __forceinline__ void fma2(float2& a, float s, const float2& w) {
    a.x = fmaf(s, w.x, a.x); a.y = fmaf(s, w.y, a.y);
}

// ---------------- CSR build (no global per-node histogram!) ----------------
__global__ __launch_bounds__(512) void init_small(int* __restrict__ bkcnt,
                                                  int* __restrict__ bcur) {
    int t = threadIdx.x;
    bkcnt[t] = 0;
    bcur[t] = 0;
}

// coarse bucket counts: LDS hist over 391 buckets, <=391 global atomics/block
__global__ __launch_bounds__(256) void bucket_count(const int* __restrict__ dst,
                                                    int* __restrict__ bkcnt) {
    __shared__ int lh[NBUCK];
    int t = threadIdx.x;
    for (int b = t; b < NBUCK; b += 256) lh[b] = 0;
    __syncthreads();
    int e0 = blockIdx.x * 4096;
#pragma unroll
    for (int i = 0; i < 16; ++i) {
        int e = e0 + i * 256 + t;
        if (e < NE) atomicAdd(&lh[dst[e] >> 8], 1);
    }
    __syncthreads();
    for (int b = t; b < NBUCK; b += 256)
        if (lh[b]) atomicAdd(&bkcnt[b], lh[b]);
}

// exclusive scan of the 391 bucket counts -> bb0; bb0[NBUCK] = NE
__global__ __launch_bounds__(512) void scan2(const int* __restrict__ bkcnt,
                                             int* __restrict__ bb0) {
    __shared__ int sh[512];
    int t = threadIdx.x;
    int val = (t < NBUCK) ? bkcnt[t] : 0;
    sh[t] = val;
    __syncthreads();
    for (int off = 1; off < 512; off <<= 1) {
        int x = (t >= off) ? sh[t - off] : 0;
        __syncthreads();
        sh[t] += x;
        __syncthreads();
    }
    bb0[t] = sh[t] - val;  // exclusive; bb0[NBUCK] == NE
}

// phase 1: radix binning by dst>>8 into per-(block,bucket) contiguous runs
__global__ __launch_bounds__(256) void bin_kernel(const int* __restrict__ src,
                                                  const int* __restrict__ dst,
                                                  const int* __restrict__ bb0,
                                                  int* __restrict__ bcur,
                                                  unsigned int* __restrict__ bucketed) {
    __shared__ int lh[NBUCK];
    __shared__ int lbase[NBUCK];
    __shared__ int lcur[NBUCK];
    int t = threadIdx.x;
    for (int b = t; b < NBUCK; b += 256) lh[b] = 0;
    __syncthreads();
    int e0 = blockIdx.x * 4096;
#pragma unroll
    for (int i = 0; i < 16; ++i) {
        int e = e0 + i * 256 + t;
        if (e < NE) atomicAdd(&lh[dst[e] >> 8], 1);
    }
    __syncthreads();
    for (int b = t; b < NBUCK; b += 256) {
        lbase[b] = bb0[b] + atomicAdd(&bcur[b], lh[b]);
        lcur[b] = 0;
    }
    __syncthreads();
#pragma unroll
    for (int i = 0; i < 16; ++i) {
        int e = e0 + i * 256 + t;
        if (e < NE) {
            int d = dst[e], s = src[e];
            int b = d >> 8;
            int pos = lbase[b] + atomicAdd(&lcur[b], 1);
            bucketed[pos] = (unsigned int)s | ((unsigned int)(d & 255) << 24);
        }
    }
}

// phase 2 (fused): per bucket -> dst-low hist + scan => row_start & dinv,
// then LDS-cursor scatter into the bucket's contiguous sorted_src window.
__global__ __launch_bounds__(256) void fine_scatter_fused(const unsigned int* __restrict__ bucketed,
                                                          const int* __restrict__ bb0,
                                                          int* __restrict__ row_start,
                                                          float* __restrict__ dinv,
                                                          int* __restrict__ sorted_src) {
    __shared__ int hist[256];
    __shared__ int sc[256];
    __shared__ int rsl[256];
    __shared__ int lcur[256];
    int b = blockIdx.x, t = threadIdx.x;
    hist[t] = 0; lcur[t] = 0;
    __syncthreads();
    int e0 = bb0[b], e1 = bb0[b + 1];
    for (int e = e0 + t; e < e1; e += 256)
        atomicAdd(&hist[bucketed[e] >> 24], 1);
    __syncthreads();
    int val = hist[t];
    sc[t] = val;
    __syncthreads();
    for (int off = 1; off < 256; off <<= 1) {
        int x = (t >= off) ? sc[t - off] : 0;
        __syncthreads();
        sc[t] += x;
        __syncthreads();
    }
    int ex = sc[t] - val;            // exclusive scan of dst-low counts
    int node = b * 256 + t;
    if (node < NN) {
        row_start[node] = e0 + ex;
        dinv[node] = rsqrtf(1.0f + (float)val);
    }
    if (node == NN) row_start[NN] = NE;
    rsl[t] = e0 + ex;
    __syncthreads();
    for (int e = e0 + t; e < e1; e += 256) {
        unsigned int p = bucketed[e];
        int dl = (int)(p >> 24);
        int pos = rsl[dl] + atomicAdd(&lcur[dl], 1);
        sorted_src[pos] = (int)(p & 0xFFFFFFu);
    }
}

// ---------------- GEMMs: reg-blocked 4x4, W staged in LDS, unroll capped ------
__global__ __launch_bounds__(256) void gemm_128_64_v3(const float* __restrict__ x,
                                                      const float* __restrict__ W,
                                                      const float* __restrict__ dinv,
                                                      unsigned short* __restrict__ hs) {
    __shared__ float xs[64][132];
    __shared__ float ws[128][64];
    int tid = threadIdx.x;
    int bn = blockIdx.x * 64;
    for (int id = tid; id < 2048; id += 256) {
        int r = id >> 4, c4 = id & 15;
        *(float4*)&ws[r][c4 * 4] = *(const float4*)(W + r * 64 + c4 * 4);
    }
    for (int id = tid; id < 64 * 33; id += 256) {
        int r = id / 33, c4 = id - r * 33;
        int n = bn + r; if (n >= NN) n = NN - 1;
        float4 v = make_float4(0.f, 0.f, 0.f, 0.f);
        if (c4 < 32) v = *(const float4*)(x + (size_t)n * 128 + c4 * 4);
        *(float4*)&xs[r][c4 * 4] = v;
    }
    __syncthreads();
    int tn = tid >> 4, tf = tid & 15;
    int f0 = tf * 4;
    float4 acc[4] = {{0,0,0,0},{0,0,0,0},{0,0,0,0},{0,0,0,0}};
#pragma unroll 2
    for (int k = 0; k < 128; k += 4) {
        float4 w0 = *(const float4*)&ws[k + 0][f0];
        float4 w1 = *(const float4*)&ws[k + 1][f0];
        float4 w2 = *(const float4*)&ws[k + 2][f0];
        float4 w3 = *(const float4*)&ws[k + 3][f0];
#pragma unroll
        for (int i = 0; i < 4; ++i) {
            float4 xa = *(const float4*)&xs[tn * 4 + i][k];
            fma4(acc[i], xa.x, w0); fma4(acc[i], xa.y, w1);
            fma4(acc[i], xa.z, w2); fma4(acc[i], xa.w, w3);
        }
    }
#pragma unroll
    for (int i = 0; i < 4; ++i) {
        int n = bn + tn * 4 + i;
        if (n < NN) {
            float di = dinv[n];
            ushort4 u;
            u.x = f2bf(acc[i].x * di); u.y = f2bf(acc[i].y * di);
            u.z = f2bf(acc[i].z * di); u.w = f2bf(acc[i].w * di);
            *(ushort4*)(hs + (size_t)n * 64 + f0) = u;
        }
    }
}

__global__ __launch_bounds__(256) void gemm_64_64_v3(const float* __restrict__ x,
                                                     const float* __restrict__ W,
                                                     const float* __restrict__ dinv,
                                                     unsigned short* __restrict__ hs) {
    __shared__ float xs[64][68];
    __shared__ float ws[64][64];
    int tid = threadIdx.x;
    int bn = blockIdx.x * 64;
    for (int id = tid; id < 1024; id += 256) {
        int r = id >> 4, c4 = id & 15;
        *(float4*)&ws[r][c4 * 4] = *(const float4*)(W + r * 64 + c4 * 4);
    }
    for (int id = tid; id < 64 * 17; id += 256) {
        int r = id / 17, c4 = id - r * 17;
        int n = bn + r; if (n >= NN) n = NN - 1;
        float4 v = make_float4(0.f, 0.f, 0.f, 0.f);
        if (c4 < 16) v = *(const float4*)(x + (size_t)n * 64 + c4 * 4);
        *(float4*)&xs[r][c4 * 4] = v;
    }
    __syncthreads();
    int tn = tid >> 4, tf = tid & 15;
    int f0 = tf * 4;
    float4 acc[4] = {{0,0,0,0},{0,0,0,0},{0,0,0,0},{0,0,0,0}};
#pragma unroll 2
    for (int k = 0; k < 64; k += 4) {
        float4 w0 = *(const float4*)&ws[k + 0][f0];
        float4 w1 = *(const float4*)&ws[k + 1][f0];
        float4 w2 = *(const float4*)&ws[k + 2][f0];
        float4 w3 = *(const float4*)&ws[k + 3][f0];
#pragma unroll
        for (int i = 0; i < 4; ++i) {
            float4 xa = *(const float4*)&xs[tn * 4 + i][k];
            fma4(acc[i], xa.x, w0); fma4(acc[i], xa.y, w1);
            fma4(acc[i], xa.z, w2); fma4(acc[i], xa.w, w3);
        }
    }
#pragma unroll
    for (int i = 0; i < 4; ++i) {
        int n = bn + tn * 4 + i;
        if (n < NN) {
            float di = dinv[n];
            ushort4 u;
            u.x = f2bf(acc[i].x * di); u.y = f2bf(acc[i].y * di);
            u.z = f2bf(acc[i].z * di); u.w = f2bf(acc[i].w * di);
            *(ushort4*)(hs + (size_t)n * 64 + f0) = u;
        }
    }
}

__global__ __launch_bounds__(256) void gemm_64_16_v3(const float* __restrict__ x,
                                                     const float* __restrict__ W,
                                                     const float* __restrict__ dinv,
                                                     unsigned short* __restrict__ hs) {
    __shared__ float xs[128][68];
    __shared__ float ws[64][16];
    int tid = threadIdx.x;
    int bn = blockIdx.x * 128;
    for (int id = tid; id < 256; id += 256) {
        int r = id >> 2, c4 = id & 3;
        *(float4*)&ws[r][c4 * 4] = *(const float4*)(W + r * 16 + c4 * 4);
    }
    for (int id = tid; id < 128 * 17; id += 256) {
        int r = id / 17, c4 = id - r * 17;
        int n = bn + r; if (n >= NN) n = NN - 1;
        float4 v = make_float4(0.f, 0.f, 0.f, 0.f);
        if (c4 < 16) v = *(const float4*)(x + (size_t)n * 64 + c4 * 4);
        *(float4*)&xs[r][c4 * 4] = v;
    }
    __syncthreads();
    int tn = tid >> 3, tf = tid & 7;
    int f0 = tf * 2;
    float2 acc[4] = {{0,0},{0,0},{0,0},{0,0}};
#pragma unroll 2
    for (int k = 0; k < 64; k += 4) {
        float2 w0 = *(const float2*)&ws[k + 0][f0];
        float2 w1 = *(const float2*)&ws[k + 1][f0];
        float2 w2 = *(const float2*)&ws[k + 2][f0];
        float2 w3 = *(const float2*)&ws[k + 3][f0];
#pragma unroll
        for (int i = 0; i < 4; ++i) {
            float4 xa = *(const float4*)&xs[tn * 4 + i][k];
            fma2(acc[i], xa.x, w0); fma2(acc[i], xa.y, w1);
            fma2(acc[i], xa.z, w2); fma2(acc[i], xa.w, w3);
        }
    }
#pragma unroll
    for (int i = 0; i < 4; ++i) {
        int n = bn + tn * 4 + i;
        if (n < NN) {
            float di = dinv[n];
            ushort2 u;
            u.x = f2bf(acc[i].x * di); u.y = f2bf(acc[i].y * di);
            *(ushort2*)(hs + (size_t)n * 16 + f0) = u;
        }
    }
}

// ---------------- CSR aggregation (bf16 gather, fp32 accum, fused epilogue) ----
__global__ __launch_bounds__(256) void csr_agg64_bn_relu(const int* __restrict__ rs,
                                                         const int* __restrict__ ss,
                                                         const unsigned short* __restrict__ hs,
                                                         const float* __restrict__ dinv,
                                                         const float* __restrict__ b,
                                                         const float* __restrict__ g,
                                                         const float* __restrict__ be,
                                                         const float* __restrict__ m,
                                                         const float* __restrict__ v,
                                                         float* __restrict__ out) {
    int lane = threadIdx.x & 63;
    int r = blockIdx.x * 4 + (threadIdx.x >> 6);
    int e0 = rs[r], e1 = rs[r + 1];
    float a0 = bf2f(hs[(size_t)r * 64 + lane]);  // self loop
    float a1 = 0.f, a2 = 0.f, a3 = 0.f;
    for (int base = e0; base < e1; base += 64) {
        int nb = e1 - base; if (nb > 64) nb = 64;
        int sidx = (lane < nb) ? ss[base + lane] : 0;
        int j = 0;
        for (; j + 4 <= nb; j += 4) {
            int s0 = __shfl(sidx, j),     s1 = __shfl(sidx, j + 1);
            int s2 = __shfl(sidx, j + 2), s3 = __shfl(sidx, j + 3);
            a0 += bf2f(hs[(size_t)s0 * 64 + lane]);
            a1 += bf2f(hs[(size_t)s1 * 64 + lane]);
            a2 += bf2f(hs[(size_t)s2 * 64 + lane]);
            a3 += bf2f(hs[(size_t)s3 * 64 + lane]);
        }
        for (; j < nb; ++j)
            a0 += bf2f(hs[(size_t)__shfl(sidx, j) * 64 + lane]);
    }
    float acc = (a0 + a1) + (a2 + a3);
    float h = dinv[r] * acc + b[lane];
    h = g[lane] * (h - m[lane]) * rsqrtf(v[lane] + EPSBN) + be[lane];
    out[(size_t)r * 64 + lane] = fmaxf(h, 0.f);
}

__global__ __launch_bounds__(256) void csr_agg16_sigmoid(const int* __restrict__ rs,
                                                         const int* __restrict__ ss,
                                                         const unsigned short* __restrict__ hs,
                                                         const float* __restrict__ dinv,
                                                         const float* __restrict__ b,
                                                         float* __restrict__ out) {
    int lane = threadIdx.x & 63;
    int wid = blockIdx.x * 4 + (threadIdx.x >> 6);
    int grp = lane >> 4, fl = lane & 15;
    int r = wid * 4 + grp;
    int e0 = rs[r], e1 = rs[r + 1];
    float a0 = bf2f(hs[(size_t)r * 16 + fl]);  // self loop
    float a1 = 0.f, a2 = 0.f, a3 = 0.f;
    for (int base = e0; base < e1; base += 16) {
        int nb = e1 - base; if (nb > 16) nb = 16;
        int sidx = (fl < nb) ? ss[base + fl] : 0;
        int j = 0;
        for (; j + 4 <= nb; j += 4) {
            int s0 = __shfl(sidx, grp * 16 + j),     s1 = __shfl(sidx, grp * 16 + j + 1);
            int s2 = __shfl(sidx, grp * 16 + j + 2), s3 = __shfl(sidx, grp * 16 + j + 3);
            a0 += bf2f(hs[(size_t)s0 * 16 + fl]);
            a1 += bf2f(hs[(size_t)s1 * 16 + fl]);
            a2 += bf2f(hs[(size_t)s2 * 16 + fl]);
            a3 += bf2f(hs[(size_t)s3 * 16 + fl]);
        }
        for (; j < nb; ++j)
            a0 += bf2f(hs[(size_t)__shfl(sidx, grp * 16 + j) * 16 + fl]);
    }
    float acc = (a0 + a1) + (a2 + a3);
    float h = dinv[r] * acc + b[fl];
    out[(size_t)r * 16 + fl] = 1.0f / (1.0f + expf(-h));
}

extern "C" void kernel_launch(void* const* d_in, const int* in_sizes, int n_in,
                              void* d_out, int out_size, void* d_ws, size_t ws_size,
                              hipStream_t stream) {
    const float* x   = (const float*)d_in[0];
    const int*   ei  = (const int*)d_in[1];   // [2, E]: src = ei, dst = ei + NE
    const float* W1  = (const float*)d_in[2];
    const float* b1  = (const float*)d_in[3];
    const float* W2  = (const float*)d_in[4];
    const float* b2  = (const float*)d_in[5];
    const float* W3  = (const float*)d_in[6];
    const float* b3  = (const float*)d_in[7];
    const float* g1  = (const float*)d_in[8];
    const float* be1 = (const float*)d_in[9];
    const float* m1  = (const float*)d_in[10];
    const float* v1  = (const float*)d_in[11];
    const float* g2  = (const float*)d_in[12];
    const float* be2 = (const float*)d_in[13];
    const float* m2  = (const float*)d_in[14];
    const float* v2  = (const float*)d_in[15];
    float* out = (float*)d_out;

    const int* srcp = ei;
    const int* dstp = ei + NE;

    // workspace layout
    float* dinv = (float*)d_ws;                          // NN
    float* A    = dinv + NN;                             // NN*64 f32 activations
    unsigned short* Bh = (unsigned short*)(A + (size_t)NN * 64);  // NN*64 bf16 hs
    int* row_start  = (int*)(Bh + (size_t)NN * 64);      // NN+1
    int* bkcnt      = row_start + NN + 2;                // 512
    int* bb0        = bkcnt + 512;                       // 512
    int* bcur       = bb0 + 512;                         // 512
    int* sorted_src = bcur + 512;                        // NE
    unsigned int* bucketed = (unsigned int*)(sorted_src + NE);  // NE

    dim3 blk(256);
    int gBIN  = (NE + 4095) / 4096;  // 391
    int gG1   = (NN + 63) / 64;      // 1563
    int gG3   = (NN + 127) / 128;    // 782
    int gA64  = NN / 4;              // 25000
    int gA16  = NN / 16;             // 6250

    // CSR build (two-phase radix by dst; per-node hist fused into fine scatter)
    init_small<<<1, 512, 0, stream>>>(bkcnt, bcur);
    bucket_count<<<gBIN, blk, 0, stream>>>(dstp, bkcnt);
    scan2<<<1, 512, 0, stream>>>(bkcnt, bb0);
    bin_kernel<<<gBIN, blk, 0, stream>>>(srcp, dstp, bb0, bcur, bucketed);
    fine_scatter_fused<<<NBUCK, blk, 0, stream>>>(bucketed, bb0, row_start, dinv, sorted_src);

    // layer 1
    gemm_128_64_v3<<<gG1, blk, 0, stream>>>(x, W1, dinv, Bh);
    csr_agg64_bn_relu<<<gA64, blk, 0, stream>>>(row_start, sorted_src, Bh, dinv,
                                                b1, g1, be1, m1, v1, A);
    // layer 2
    gemm_64_64_v3<<<gG1, blk, 0, stream>>>(A, W2, dinv, Bh);
    csr_agg64_bn_relu<<<gA64, blk, 0, stream>>>(row_start, sorted_src, Bh, dinv,
                                                b2, g2, be2, m2, v2, A);
    // layer 3
    gemm_64_16_v3<<<gG3, blk, 0, stream>>>(A, W3, dinv, Bh);
    csr_agg16_sigmoid<<<gA16, blk, 0, stream>>>(row_start, sorted_src, Bh, dinv, b3, out);
}